// Round 9
// baseline (2477.739 us; speedup 1.0000x reference)
//
#include <hip/hip_runtime.h>
#include <math.h>

namespace {

constexpr int S = 128;   // seq
constexpr int B = 128;   // batch
constexpr int E = 256;   // embed
constexpr int H = 256;   // hidden

typedef unsigned short u16;
typedef unsigned long long u64;
typedef __attribute__((ext_vector_type(8))) short short8v;   // 8 bf16
typedef __attribute__((ext_vector_type(4))) float f32x4;
typedef __attribute__((ext_vector_type(4))) unsigned uint4v;

__device__ __forceinline__ float sigmoidf(float x) { return 1.0f / (1.0f + expf(-x)); }
__device__ __forceinline__ u16 bf16rnd(float x) {
  unsigned u = __float_as_uint(x);
  return (u16)((u + 0x7FFFu + ((u >> 16) & 1u)) >> 16);
}
__device__ __forceinline__ float bf2f(u16 v) { return __uint_as_float(((unsigned)v) << 16); }
__device__ __forceinline__ void split2(float x, u16& h, u16& l) {
  h = bf16rnd(x);
  l = bf16rnd(x - bf2f(h));
}
// gate-interleaved column mapping: col c in [0,1024) -> original W row
__device__ __forceinline__ int gcol_of(int c) {
  return ((c >> 4) & 3) * 256 + ((c & 15) + ((c >> 6) << 4));
}

// ================== split / prep kernels ==================

__global__ void split_pair(const float* __restrict__ src, u16* __restrict__ h,
                           u16* __restrict__ l, long n) {
  long i = (long)blockIdx.x * 256 + threadIdx.x;
  if (i < n) split2(src[i], h[i], l[i]);
}

__global__ void split_w_int(const float* __restrict__ W, u16* __restrict__ h,
                            u16* __restrict__ l) {
  int i = blockIdx.x * 256 + threadIdx.x;   // 1024*256
  int c = i >> 8, k = i & 255;
  split2(W[gcol_of(c) * 256 + k], h[i], l[i]);
}

__global__ void make_bint(const float* __restrict__ bih, const float* __restrict__ bhh,
                          float* __restrict__ bint) {
  int c = blockIdx.x * 256 + threadIdx.x;   // 1024
  int g = gcol_of(c);
  bint[c] = bih[g] + bhh[g];
}

// h state packed: hP[elem] = (hi16 << 16) | lo16
__global__ void init_hc(const float* hQ, const float* cQ, const float* hC, const float* cC,
                        const float* hC2, const float* cC2,
                        unsigned* hP, float* cst) {
  int i = blockIdx.x * 256 + threadIdx.x;
  if (i >= 6 * B * H) return;
  int z = i / (B * H);
  int rem = i - z * (B * H);
  int input = z >> 1, dir = z & 1;
  const float* hs = input == 0 ? hQ : (input == 1 ? hC : hC2);
  const float* cs = input == 0 ? cQ : (input == 1 ? cC : cC2);
  u16 hh, hl;
  split2(hs[dir * B * H + rem], hh, hl);
  hP[i] = ((unsigned)hh << 16) | hl;
  cst[i] = cs[dir * B * H + rem];
}

__global__ void zero_gen(int* gen) {
  if (threadIdx.x < 6) gen[threadIdx.x * 256] = 0;   // 1KB-padded counters
}

// ================== MFMA split-bf16 GEMM kernels ==================
// 256 thr = 4 waves (2x2), block tile 128x128, wave tile 64x64
// = 4x4 MFMA 16x16x32 tiles, K staged in chunks of 32, LDS pitch 40 bf16.
// Fragment maps (gfx950 mfma_f32_16x16x32_bf16):
//   A: row = lane&15, k = (lane>>4)*8 + j    B: col = lane&15, same k
//   D: row = (lane>>4)*4 + reg, col = lane&15   [m89-verified]

#define MFMA_PROLOG                                        \
  const int tid = threadIdx.x;                             \
  const int wave = tid >> 6, lane = tid & 63;              \
  const int wr = wave >> 1, wc = wave & 1;                 \
  const int lrow = lane & 15, lk = lane >> 4;              \
  f32x4 acc[4][4];

#define MFMA_ZERO_ACC                                      \
  _Pragma("unroll") for (int a_ = 0; a_ < 4; ++a_)         \
  _Pragma("unroll") for (int b_ = 0; b_ < 4; ++b_)         \
      acc[a_][b_] = (f32x4){0.f, 0.f, 0.f, 0.f};

#define MFMA_INNER                                                             \
  __syncthreads();                                                             \
  short8v ah[4], al[4];                                                        \
  _Pragma("unroll") for (int mt = 0; mt < 4; ++mt) {                           \
    int r_ = wr * 64 + mt * 16 + lrow;                                         \
    ah[mt] = *(const short8v*)&Ah[r_ * 40 + lk * 8];                           \
    al[mt] = *(const short8v*)&Al[r_ * 40 + lk * 8];                           \
  }                                                                            \
  _Pragma("unroll") for (int nt = 0; nt < 4; ++nt) {                           \
    int c_ = wc * 64 + nt * 16 + lrow;                                         \
    short8v bh = *(const short8v*)&Bh[c_ * 40 + lk * 8];                       \
    short8v bl = *(const short8v*)&Bl[c_ * 40 + lk * 8];                       \
    _Pragma("unroll") for (int mt = 0; mt < 4; ++mt) {                         \
      acc[mt][nt] = __builtin_amdgcn_mfma_f32_16x16x32_bf16(ah[mt], bh, acc[mt][nt], 0, 0, 0); \
      acc[mt][nt] = __builtin_amdgcn_mfma_f32_16x16x32_bf16(ah[mt], bl, acc[mt][nt], 0, 0, 0); \
      acc[mt][nt] = __builtin_amdgcn_mfma_f32_16x16x32_bf16(al[mt], bh, acc[mt][nt], 0, 0, 0); \
    }                                                                          \
  }

// ---- fused persistent LSTM: all 128 steps, x-projection in-kernel ----
// grid 128 blocks: z = bx%8 (z>=6 exit), nb = bx>>3. Block tile M=128 x N=64
// interleaved gate-cols; 4 waves over m (32 rows each). Wih+Whh slices LDS-resident.
// h exchange: RELAXED agent-scope atomics (write-through to MALL, no L2
// writeback/invalidate sweeps) + per-z counter. Cell state in registers.
__global__ __launch_bounds__(256) void lstm_fused(
    const int* __restrict__ idxQ, const int* __restrict__ idxC, const int* __restrict__ idxC2,
    const u16* __restrict__ embH, const u16* __restrict__ embL,
    const u16* __restrict__ wihHf, const u16* __restrict__ wihLf,
    const u16* __restrict__ wihHb, const u16* __restrict__ wihLb,
    const u16* __restrict__ whhHf, const u16* __restrict__ whhLf,
    const u16* __restrict__ whhHb, const u16* __restrict__ whhLb,
    const float* __restrict__ bintf, const float* __restrict__ bintb,
    unsigned* __restrict__ hP, const float* __restrict__ cst0,
    u16* __restrict__ out3h, u16* __restrict__ out3l,
    int* __restrict__ gen)
{
  const int bx = blockIdx.x;
  const int z = bx & 7;
  if (z >= 6) return;
  const int nb = bx >> 3;
  const int input = z >> 1, dir = z & 1;
  const int n0c = nb * 64;                 // interleaved col base
  const int tid = threadIdx.x;
  const int wave = tid >> 6, lane = tid & 63;
  const int lrow = lane & 15, lk = lane >> 4;
  const int wr = wave;                     // 4 waves over m: rows wr*32..+31
  const int* idx = input == 0 ? idxQ : (input == 1 ? idxC : idxC2);
  const u16* wiHp = dir ? wihHb : wihHf;
  const u16* wiLp = dir ? wihLb : wihLf;
  const u16* whHp = dir ? whhHb : whhHf;
  const u16* whLp = dir ? whhLb : whhLf;
  const float* bint = dir ? bintb : bintf;

  __shared__ __align__(16) short WiH[64 * 264], WiL[64 * 264];   // pitch 264
  __shared__ __align__(16) short WhH[64 * 264], WhL[64 * 264];

  // one-time W slice loads (amortized over 128 steps)
#pragma unroll
  for (int i = 0; i < 8; ++i) {
    int e = i * 256 + tid;                 // 2048 chunks of 8 bf16 per array
    int c = e >> 5, kc = e & 31;
    long src = (long)(n0c + c) * 256 + kc * 8;
    *(short8v*)&WiH[c * 264 + kc * 8] = *(const short8v*)(wiHp + src);
    *(short8v*)&WiL[c * 264 + kc * 8] = *(const short8v*)(wiLp + src);
    *(short8v*)&WhH[c * 264 + kc * 8] = *(const short8v*)(whHp + src);
    *(short8v*)&WhL[c * 264 + kc * 8] = *(const short8v*)(whLp + src);
  }

  // static per-thread state
  const int u = nb * 16 + lrow;            // unit (0..255); gate == nt
  float bintv[4];
#pragma unroll
  for (int nt = 0; nt < 4; ++nt) bintv[nt] = bint[n0c + nt * 16 + lrow];

  const long HS6 = (long)6 * B * H;
  const long zb = (long)z * B * H;
  float creg[2][4];                        // cell state: register-resident all 128 steps
#pragma unroll
  for (int mt = 0; mt < 2; ++mt)
#pragma unroll
    for (int rg = 0; rg < 4; ++rg)
      creg[mt][rg] = cst0[zb + (long)(wr * 32 + mt * 16 + lk * 4 + rg) * H + u];

  int* genz = gen + z * 256;               // 1KB padded counter
  u16* o3h = out3h + (long)input * B * S * 512;
  u16* o3l = out3l + (long)input * B * S * 512;

  __syncthreads();                         // W LDS ready

  for (int t = 0; t < S; ++t) {
    const int t_eff = dir ? (S - 1 - t) : t;
    const int par = t & 1;

    // token ids straight from (L2-hot, read-only) idx — no LDS staging
    const int tv0 = idx[t_eff * B + wr * 32 + lrow];
    const int tv1 = idx[t_eff * B + wr * 32 + 16 + lrow];

    f32x4 acc[2][4];
#pragma unroll
    for (int mt = 0; mt < 2; ++mt)
#pragma unroll
      for (int nt = 0; nt < 4; ++nt)
        acc[mt][nt] = (f32x4){bintv[nt], bintv[nt], bintv[nt], bintv[nt]};

    // ---- x-part: emb[tok] @ WihI^T (h-independent -> hides the barrier wait) ----
#pragma unroll
    for (int kb = 0; kb < 8; ++kb) {
      short8v ah[2], al[2];
      {
        long e0 = (long)tv0 * 256 + kb * 32 + lk * 8;
        long e1 = (long)tv1 * 256 + kb * 32 + lk * 8;
        ah[0] = *(const short8v*)(embH + e0);
        al[0] = *(const short8v*)(embL + e0);
        ah[1] = *(const short8v*)(embH + e1);
        al[1] = *(const short8v*)(embL + e1);
      }
#pragma unroll
      for (int nt = 0; nt < 4; ++nt) {
        int c = nt * 16 + lrow;
        short8v bh = *(const short8v*)&WiH[c * 264 + kb * 32 + lk * 8];
        short8v bl = *(const short8v*)&WiL[c * 264 + kb * 32 + lk * 8];
#pragma unroll
        for (int mt = 0; mt < 2; ++mt) {
          acc[mt][nt] = __builtin_amdgcn_mfma_f32_16x16x32_bf16(ah[mt], bh, acc[mt][nt], 0, 0, 0);
          acc[mt][nt] = __builtin_amdgcn_mfma_f32_16x16x32_bf16(ah[mt], bl, acc[mt][nt], 0, 0, 0);
          acc[mt][nt] = __builtin_amdgcn_mfma_f32_16x16x32_bf16(al[mt], bh, acc[mt][nt], 0, 0, 0);
        }
      }
    }

    // ---- wait for h(t-1): 16 relaxed arrivals per z per step ----
    if (t > 0) {
      if (tid == 0) {
        const int target = 16 * t;
        while (__hip_atomic_load(genz, __ATOMIC_RELAXED, __HIP_MEMORY_SCOPE_AGENT) < target) {
          __builtin_amdgcn_s_sleep(1);
        }
      }
      __syncthreads();
    }

    // ---- h-part: h(t-1) @ WhhI^T; h read as packed u32 via relaxed agent atomics ----
    const unsigned* hr = hP + (long)par * HS6 + zb;
#pragma unroll
    for (int kb = 0; kb < 8; ++kb) {
      short8v ah[2], al[2];
#pragma unroll
      for (int mt = 0; mt < 2; ++mt) {
        long base = (long)(wr * 32 + mt * 16 + lrow) * 256 + kb * 32 + lk * 8;
        const u64* p = (const u64*)(hr + base);
        uint4v hi, lo;
#pragma unroll
        for (int j = 0; j < 4; ++j) {
          u64 q = __hip_atomic_load(p + j, __ATOMIC_RELAXED, __HIP_MEMORY_SCOPE_AGENT);
          unsigned a = (unsigned)q, b = (unsigned)(q >> 32);
          hi[j] = (a >> 16) | (b & 0xffff0000u);
          lo[j] = (a & 0xffffu) | (b << 16);
        }
        ah[mt] = __builtin_bit_cast(short8v, hi);
        al[mt] = __builtin_bit_cast(short8v, lo);
      }
#pragma unroll
      for (int nt = 0; nt < 4; ++nt) {
        int c = nt * 16 + lrow;
        short8v bh = *(const short8v*)&WhH[c * 264 + kb * 32 + lk * 8];
        short8v bl = *(const short8v*)&WhL[c * 264 + kb * 32 + lk * 8];
#pragma unroll
        for (int mt = 0; mt < 2; ++mt) {
          acc[mt][nt] = __builtin_amdgcn_mfma_f32_16x16x32_bf16(ah[mt], bh, acc[mt][nt], 0, 0, 0);
          acc[mt][nt] = __builtin_amdgcn_mfma_f32_16x16x32_bf16(ah[mt], bl, acc[mt][nt], 0, 0, 0);
          acc[mt][nt] = __builtin_amdgcn_mfma_f32_16x16x32_bf16(al[mt], bh, acc[mt][nt], 0, 0, 0);
        }
      }
    }

    // ---- gates (nt == gate: i,f,g,o); c in registers; publish h write-through ----
    unsigned* hw = hP + (long)(par ^ 1) * HS6 + zb;
    u16 oh[2][4], ol[2][4];
#pragma unroll
    for (int mt = 0; mt < 2; ++mt)
#pragma unroll
      for (int rg = 0; rg < 4; ++rg) {
        int row = wr * 32 + mt * 16 + lk * 4 + rg;
        float ig = sigmoidf(acc[mt][0][rg]);
        float fg = sigmoidf(acc[mt][1][rg]);
        float gg = tanhf(acc[mt][2][rg]);
        float og = sigmoidf(acc[mt][3][rg]);
        float cn = fg * creg[mt][rg] + ig * gg;
        creg[mt][rg] = cn;
        float hn = og * tanhf(cn);
        u16 hh, hl;
        split2(hn, hh, hl);
        oh[mt][rg] = hh; ol[mt][rg] = hl;
        __hip_atomic_store(&hw[(long)row * H + u], ((unsigned)hh << 16) | hl,
                           __ATOMIC_RELAXED, __HIP_MEMORY_SCOPE_AGENT);
      }

    // drain h stores (per wave), block-align, single relaxed arrival
    asm volatile("s_waitcnt vmcnt(0)" ::: "memory");
    __syncthreads();
    if (tid == 0) {
      __hip_atomic_fetch_add(genz, 1, __ATOMIC_RELAXED, __HIP_MEMORY_SCOPE_AGENT);
    }

    // out3 stores AFTER publish — off the critical drain; consumed post-kernel
#pragma unroll
    for (int mt = 0; mt < 2; ++mt)
#pragma unroll
      for (int rg = 0; rg < 4; ++rg) {
        int row = wr * 32 + mt * 16 + lk * 4 + rg;
        long oi = ((long)row * S + t_eff) * 512 + dir * 256 + u;
        o3h[oi] = oh[mt][rg];
        o3l[oi] = ol[mt][rg];
      }
  }
}

// ---- Ct = tanh(C0 @ S1W^T + S1b), output split hi/lo ----
// grid (4, 128), block 256. M=16384, N=512, K=512.
__global__ __launch_bounds__(256) void ct_mfma(
    const u16* __restrict__ aH, const u16* __restrict__ aL,
    const u16* __restrict__ s1H, const u16* __restrict__ s1L,
    const float* __restrict__ s1b,
    u16* __restrict__ ctH, u16* __restrict__ ctL)
{
  const int n0 = blockIdx.x * 128, m0 = blockIdx.y * 128;
  __shared__ __align__(16) short Ah[128 * 40], Al[128 * 40], Bh[128 * 40], Bl[128 * 40];
  MFMA_PROLOG
  MFMA_ZERO_ACC

  for (int kb = 0; kb < 512; kb += 32) {
    __syncthreads();
#pragma unroll
    for (int i = 0; i < 2; ++i) {
      int e = i * 256 + tid;
      int r = e >> 2, kg = e & 3;
      long abase = (long)(m0 + r) * 512 + kb + kg * 8;
      *(short8v*)&Ah[r * 40 + kg * 8] = *(const short8v*)(aH + abase);
      *(short8v*)&Al[r * 40 + kg * 8] = *(const short8v*)(aL + abase);
      long bbase = (long)(n0 + r) * 512 + kb + kg * 8;
      *(short8v*)&Bh[r * 40 + kg * 8] = *(const short8v*)(s1H + bbase);
      *(short8v*)&Bl[r * 40 + kg * 8] = *(const short8v*)(s1L + bbase);
    }
    MFMA_INNER
  }

#pragma unroll
  for (int mt = 0; mt < 4; ++mt)
#pragma unroll
    for (int nt = 0; nt < 4; ++nt) {
      int c = n0 + wc * 64 + nt * 16 + lrow;
      float bv = s1b[c];
#pragma unroll
      for (int rg = 0; rg < 4; ++rg) {
        long m = m0 + wr * 64 + mt * 16 + lk * 4 + rg;
        u16 hh, ll;
        split2(tanhf(acc[mt][nt][rg] + bv), hh, ll);
        ctH[m * 512 + c] = hh;
        ctL[m * 512 + c] = ll;
      }
    }
}

// ---- Hm[b] = Q[b] @ Ct[b]^T (fp32 out) ----
__global__ __launch_bounds__(256) void hm_mfma(
    const u16* __restrict__ qH, const u16* __restrict__ qL,
    const u16* __restrict__ ctH, const u16* __restrict__ ctL,
    float* __restrict__ Hm)
{
  const int bb = blockIdx.x;
  const u16* aH = qH + (long)bb * S * 512;
  const u16* aL = qL + (long)bb * S * 512;
  const u16* bH = ctH + (long)bb * S * 512;
  const u16* bL = ctL + (long)bb * S * 512;
  __shared__ __align__(16) short Ah[128 * 40], Al[128 * 40], Bh[128 * 40], Bl[128 * 40];
  MFMA_PROLOG
  MFMA_ZERO_ACC

  for (int kb = 0; kb < 512; kb += 32) {
    __syncthreads();
#pragma unroll
    for (int i = 0; i < 2; ++i) {
      int e = i * 256 + tid;
      int r = e >> 2, kg = e & 3;
      long base = (long)r * 512 + kb + kg * 8;
      *(short8v*)&Ah[r * 40 + kg * 8] = *(const short8v*)(aH + base);
      *(short8v*)&Al[r * 40 + kg * 8] = *(const short8v*)(aL + base);
      *(short8v*)&Bh[r * 40 + kg * 8] = *(const short8v*)(bH + base);
      *(short8v*)&Bl[r * 40 + kg * 8] = *(const short8v*)(bL + base);
    }
    MFMA_INNER
  }

  float* out = Hm + (long)bb * S * S;
#pragma unroll
  for (int mt = 0; mt < 4; ++mt)
#pragma unroll
    for (int nt = 0; nt < 4; ++nt) {
      int c = wc * 64 + nt * 16 + lrow;
#pragma unroll
      for (int rg = 0; rg < 4; ++rg) {
        int m = wr * 64 + mt * 16 + lk * 4 + rg;
        out[(long)m * S + c] = acc[mt][nt][rg];
      }
    }
}

// ---- Qt[b][c][t] planes from o3 planes [b][t][512] (LDS tile transpose) ----
// grid (8 cblk, 2 tblk, 128 b), block 256.
__global__ void transpose_qt(const u16* __restrict__ o3h, const u16* __restrict__ o3l,
                             u16* __restrict__ qth, u16* __restrict__ qtl) {
  const int b = blockIdx.z;
  const int c0 = blockIdx.x * 64, t0 = blockIdx.y * 64;
  __shared__ u16 tile[64][72];
  const int tid = threadIdx.x;
  for (int pl = 0; pl < 2; ++pl) {
    const u16* src = (pl ? o3l : o3h) + (long)b * S * 512;
    u16* dst = (pl ? qtl : qth) + (long)b * 512 * 128;
    __syncthreads();
#pragma unroll
    for (int i = 0; i < 2; ++i) {
      int e = i * 256 + tid;
      int r = e >> 3, sg = e & 7;
      *(short8v*)&tile[r][sg * 8] = *(const short8v*)(src + (long)(t0 + r) * 512 + c0 + sg * 8);
    }
    __syncthreads();
#pragma unroll
    for (int i = 0; i < 2; ++i) {
      int e = i * 256 + tid;
      int c = e >> 3, sg = e & 7;
      short8v v;
#pragma unroll
      for (int j = 0; j < 8; ++j) v[j] = tile[sg * 8 + j][c];
      *(short8v*)(dst + (long)(c0 + c) * 128 + t0 + sg * 8) = v;
    }
  }
}

// ---- pq_mfma: C[b][128][512] = P[b][128x128] @ Bt[b][512x128]^T (K = t dim) ----
// A planes [b][m][k] pitch 128; B planes [b][c][k] pitch 128. grid (4, 1, 128).
// WRITE_T: also emit C^T as bf16 hi/lo planes [b][c][m] (for the MC chain).
template <bool WRITE_T>
__global__ __launch_bounds__(256) void pq_mfma(
    const u16* __restrict__ pH, const u16* __restrict__ pL,
    const u16* __restrict__ btH, const u16* __restrict__ btL,
    float* __restrict__ Cout, u16* __restrict__ tH, u16* __restrict__ tL)
{
  const int bb = blockIdx.z, n0 = blockIdx.x * 128;
  const u16* aHp = pH + (long)bb * 128 * 128;
  const u16* aLp = pL + (long)bb * 128 * 128;
  const u16* bHp = btH + ((long)bb * 512 + n0) * 128;
  const u16* bLp = btL + ((long)bb * 512 + n0) * 128;
  __shared__ __align__(16) short Ah[128 * 40], Al[128 * 40], Bh[128 * 40], Bl[128 * 40];
  MFMA_PROLOG
  MFMA_ZERO_ACC

  for (int kb = 0; kb < 128; kb += 32) {
    __syncthreads();
#pragma unroll
    for (int i = 0; i < 2; ++i) {
      int e = i * 256 + tid;
      int r = e >> 2, kg = e & 3;
      long base = (long)r * 128 + kb + kg * 8;
      *(short8v*)&Ah[r * 40 + kg * 8] = *(const short8v*)(aHp + base);
      *(short8v*)&Al[r * 40 + kg * 8] = *(const short8v*)(aLp + base);
      *(short8v*)&Bh[r * 40 + kg * 8] = *(const short8v*)(bHp + base);
      *(short8v*)&Bl[r * 40 + kg * 8] = *(const short8v*)(bLp + base);
    }
    MFMA_INNER
  }

  float* co = Cout + (long)bb * 128 * 512;
#pragma unroll
  for (int mt = 0; mt < 4; ++mt)
#pragma unroll
    for (int nt = 0; nt < 4; ++nt) {
      int c = n0 + wc * 64 + nt * 16 + lrow;
#pragma unroll
      for (int rg = 0; rg < 4; ++rg) {
        int m = wr * 64 + mt * 16 + lk * 4 + rg;
        float v = acc[mt][nt][rg];
        co[(long)m * 512 + c] = v;
        if (WRITE_T) {
          u16 hh, ll;
          split2(v, hh, ll);
          tH[((long)bb * 512 + c) * 128 + m] = hh;
          tL[((long)bb * 512 + c) * 128 + m] = ll;
        }
      }
    }
}

// ---------------- softmaxes ----------------
__global__ void softmax_row_bf(const float* __restrict__ Hm, u16* __restrict__ ph,
                               u16* __restrict__ pl) {
  const int row = blockIdx.x;
  const float* p = Hm + (long)row * S;
  const int l = threadIdx.x;
  float v0 = p[l], v1 = p[l + 64];
  float m = fmaxf(v0, v1);
#pragma unroll
  for (int o = 32; o > 0; o >>= 1) m = fmaxf(m, __shfl_xor(m, o));
  float e0 = expf(v0 - m), e1 = expf(v1 - m);
  float s = e0 + e1;
#pragma unroll
  for (int o = 32; o > 0; o >>= 1) s += __shfl_xor(s, o);
  float inv = 1.0f / s;
  u16 hh, ll;
  split2(e0 * inv, hh, ll);
  ph[(long)row * S + l] = hh; pl[(long)row * S + l] = ll;
  split2(e1 * inv, hh, ll);
  ph[(long)row * S + l + 64] = hh; pl[(long)row * S + l + 64] = ll;
}

__global__ void softmax_colT_bf(const float* __restrict__ Hm, u16* __restrict__ ph,
                                u16* __restrict__ pl) {
  const int b = blockIdx.x >> 7;
  const int col = blockIdx.x & 127;
  const float* p = Hm + (long)b * S * S + col;
  const int l = threadIdx.x;
  float v0 = p[(long)l * S], v1 = p[(long)(l + 64) * S];
  float m = fmaxf(v0, v1);
#pragma unroll
  for (int o = 32; o > 0; o >>= 1) m = fmaxf(m, __shfl_xor(m, o));
  float e0 = expf(v0 - m), e1 = expf(v1 - m);
  float s = e0 + e1;
#pragma unroll
  for (int o = 32; o > 0; o >>= 1) s += __shfl_xor(s, o);
  float inv = 1.0f / s;
  long q = ((long)b * S + col) * S;
  u16 hh, ll;
  split2(e0 * inv, hh, ll);
  ph[q + l] = hh; pl[q + l] = ll;
  split2(e1 * inv, hh, ll);
  ph[q + l + 64] = hh; pl[q + l + 64] = ll;
}

// fp32 softmaxes for the fallback path
__global__ void softmax_row(const float* __restrict__ Hm, float* __restrict__ A) {
  const int row = blockIdx.x;
  const float* p = Hm + (long)row * S;
  const int l = threadIdx.x;
  float v0 = p[l], v1 = p[l + 64];
  float m = fmaxf(v0, v1);
#pragma unroll
  for (int o = 32; o > 0; o >>= 1) m = fmaxf(m, __shfl_xor(m, o));
  float e0 = expf(v0 - m), e1 = expf(v1 - m);
  float s = e0 + e1;
#pragma unroll
  for (int o = 32; o > 0; o >>= 1) s += __shfl_xor(s, o);
  float inv = 1.0f / s;
  float* q = A + (long)row * S;
  q[l] = e0 * inv; q[l + 64] = e1 * inv;
}

__global__ void softmax_colT(const float* __restrict__ Hm, float* __restrict__ A) {
  const int b = blockIdx.x >> 7;
  const int col = blockIdx.x & 127;
  const float* p = Hm + (long)b * S * S + col;
  const int l = threadIdx.x;
  float v0 = p[(long)l * S], v1 = p[(long)(l + 64) * S];
  float m = fmaxf(v0, v1);
#pragma unroll
  for (int o = 32; o > 0; o >>= 1) m = fmaxf(m, __shfl_xor(m, o));
  float e0 = expf(v0 - m), e1 = expf(v1 - m);
  float s = e0 + e1;
#pragma unroll
  for (int o = 32; o > 0; o >>= 1) s += __shfl_xor(s, o);
  float inv = 1.0f / s;
  float* q = A + ((long)b * S + col) * S;
  q[l] = e0 * inv; q[l + 64] = e1 * inv;
}

// ================== FALLBACK PATH (round-1, verified) ==================

__global__ void init_state(const float* hQ, const float* cQ,
                           const float* hC, const float* cC,
                           const float* hC2, const float* cC2,
                           float* h0, float* c0) {
  int i = blockIdx.x * 256 + threadIdx.x;
  if (i >= 6 * B * H) return;
  int z = i / (B * H);
  int rem = i - z * (B * H);
  int input = z >> 1, dir = z & 1;
  const float* hs = input == 0 ? hQ : (input == 1 ? hC : hC2);
  const float* cs = input == 0 ? cQ : (input == 1 ? cC : cC2);
  h0[i] = hs[dir * B * H + rem];
  c0[i] = cs[dir * B * H + rem];
}

__global__ __launch_bounds__(256) void lstm_step(
    const int* __restrict__ idxQ, const int* __restrict__ idxC, const int* __restrict__ idxC2,
    const float* __restrict__ emb,
    const float* __restrict__ Wih_f, const float* __restrict__ Whh_f,
    const float* __restrict__ bih_f, const float* __restrict__ bhh_f,
    const float* __restrict__ Wih_b, const float* __restrict__ Whh_b,
    const float* __restrict__ bih_b, const float* __restrict__ bhh_b,
    const float* __restrict__ hread, float* __restrict__ hwrite,
    float* __restrict__ cstate, float* __restrict__ out3, int t)
{
  const int z = blockIdx.z;
  const int input = z >> 1, dir = z & 1;
  const int u0 = blockIdx.x * 16;
  const int b0 = blockIdx.y * 64;
  const int t_eff = dir ? (S - 1 - t) : t;
  const int* idx = input == 0 ? idxQ : (input == 1 ? idxC : idxC2);
  const float* Wih = dir ? Wih_b : Wih_f;
  const float* Whh = dir ? Whh_b : Whh_f;
  const float* bih = dir ? bih_b : bih_f;
  const float* bhh = dir ? bhh_b : bhh_f;

  __shared__ float Alds[64][68];
  __shared__ float Wl[64][68];
  __shared__ int tok[64];

  const int tid = threadIdx.x;
  if (tid < 64) tok[tid] = idx[t_eff * B + b0 + tid];

  const int uu = tid & 15;
  const int rg = tid >> 4;
  const int u = u0 + uu;

  float acc[4][4];
#pragma unroll
  for (int ri = 0; ri < 4; ++ri)
#pragma unroll
    for (int g = 0; g < 4; ++g)
      acc[ri][g] = bih[g * 256 + u] + bhh[g * 256 + u];

  for (int kc = 0; kc < 8; ++kc) {
    __syncthreads();
    if (kc < 4) {
      const int kb = kc * 64;
#pragma unroll
      for (int i = 0; i < 16; ++i) {
        int e = i * 256 + tid;
        int kk = e & 63, r = e >> 6;
        Alds[r][kk] = emb[(long)tok[r] * E + kb + kk];
      }
    } else {
      const int kb = (kc - 4) * 64;
      const float* hs = hread + ((long)z * B + b0) * H + kb;
#pragma unroll
      for (int i = 0; i < 16; ++i) {
        int e = i * 256 + tid;
        int kk = e & 63, r = e >> 6;
        Alds[r][kk] = hs[r * H + kk];
      }
    }
    {
      const float* Wsrc = (kc < 4) ? Wih : Whh;
      const int kb = (kc & 3) * 64;
#pragma unroll
      for (int i = 0; i < 16; ++i) {
        int e = i * 256 + tid;
        int kk = e & 63, c = e >> 6;
        int gcol = (c >> 4) * 256 + u0 + (c & 15);
        Wl[c][kk] = Wsrc[(long)gcol * H + kb + kk];
      }
    }
    __syncthreads();
#pragma unroll
    for (int k4 = 0; k4 < 64; k4 += 4) {
      float4 a[4], w[4];
#pragma unroll
      for (int ri = 0; ri < 4; ++ri) a[ri] = *(const float4*)&Alds[rg * 4 + ri][k4];
#pragma unroll
      for (int g = 0; g < 4; ++g) w[g] = *(const float4*)&Wl[g * 16 + uu][k4];
#pragma unroll
      for (int ri = 0; ri < 4; ++ri)
#pragma unroll
        for (int g = 0; g < 4; ++g)
          acc[ri][g] += a[ri].x * w[g].x + a[ri].y * w[g].y
                      + a[ri].z * w[g].z + a[ri].w * w[g].w;
    }
  }

  float* cs = cstate + (long)z * B * H;
  float* hw = hwrite + (long)z * B * H;
  float* op = out3 + (long)input * B * S * 2 * H;
#pragma unroll
  for (int ri = 0; ri < 4; ++ri) {
    int b = b0 + rg * 4 + ri;
    float ig = sigmoidf(acc[ri][0]);
    float fg = sigmoidf(acc[ri][1]);
    float gg = tanhf(acc[ri][2]);
    float og = sigmoidf(acc[ri][3]);
    float cn = fg * cs[b * H + u] + ig * gg;
    float hn = og * tanhf(cn);
    cs[b * H + u] = cn;
    hw[b * H + u] = hn;
    op[((long)b * S + t_eff) * (2 * H) + dir * H + u] = hn;
  }
}

template <bool TANH>
__global__ __launch_bounds__(256) void gemm_nt(
    const float* __restrict__ A, const float* __restrict__ B_,
    const float* __restrict__ bias, float* __restrict__ C,
    int lda, int ldb, int ldc, int K, long sA, long sB, long sC)
{
  A += blockIdx.z * sA; B_ += blockIdx.z * sB; C += blockIdx.z * sC;
  const int n0 = blockIdx.x * 64, m0 = blockIdx.y * 64;
  __shared__ float Alds[64][68], Blds[64][68];
  const int tid = threadIdx.x, uu = tid & 15, rg = tid >> 4;
  float acc[4][4] = {};
  for (int kb = 0; kb < K; kb += 64) {
    __syncthreads();
#pragma unroll
    for (int i = 0; i < 16; ++i) {
      int e = i * 256 + tid;
      int kk = e & 63, r = e >> 6;
      Alds[r][kk] = A[(long)(m0 + r) * lda + kb + kk];
      Blds[r][kk] = B_[(long)(n0 + r) * ldb + kb + kk];
    }
    __syncthreads();
#pragma unroll
    for (int k4 = 0; k4 < 64; k4 += 4) {
      float4 a[4], w[4];
#pragma unroll
      for (int ri = 0; ri < 4; ++ri) a[ri] = *(const float4*)&Alds[rg * 4 + ri][k4];
#pragma unroll
      for (int ci = 0; ci < 4; ++ci) w[ci] = *(const float4*)&Blds[ci * 16 + uu][k4];
#pragma unroll
      for (int ri = 0; ri < 4; ++ri)
#pragma unroll
        for (int ci = 0; ci < 4; ++ci)
          acc[ri][ci] += a[ri].x * w[ci].x + a[ri].y * w[ci].y
                       + a[ri].z * w[ci].z + a[ri].w * w[ci].w;
    }
  }
#pragma unroll
  for (int ri = 0; ri < 4; ++ri) {
    int m = m0 + rg * 4 + ri;
#pragma unroll
    for (int ci = 0; ci < 4; ++ci) {
      int n = n0 + ci * 16 + uu;
      float v = acc[ri][ci];
      if (bias) v += bias[n];
      if (TANH) v = tanhf(v);
      C[(long)m * ldc + n] = v;
    }
  }
}

__global__ __launch_bounds__(256) void gemm_nn(
    const float* __restrict__ A, const float* __restrict__ B_,
    float* __restrict__ C,
    int lda, int ldb, int ldc, int K, long sA, long sB, long sC)
{
  A += blockIdx.z * sA; B_ += blockIdx.z * sB; C += blockIdx.z * sC;
  const int n0 = blockIdx.x * 64, m0 = blockIdx.y * 64;
  __shared__ float Alds[64][68];
  __shared__ float Blds[64][68];
  const int tid = threadIdx.x, uu = tid & 15, rg = tid >> 4;
  float acc[4][4] = {};
  for (int kb = 0; kb < K; kb += 64) {
    __syncthreads();
#pragma unroll
    for (int i = 0; i < 16; ++i) {
      int e = i * 256 + tid;
      int kk = e & 63, r = e >> 6;
      Alds[r][kk] = A[(long)(m0 + r) * lda + kb + kk];
      Blds[r][kk] = B_[(long)(kb + r) * ldb + n0 + kk];
    }
    __syncthreads();
#pragma unroll
    for (int kk = 0; kk < 64; ++kk) {
      float4 w = *(const float4*)&Blds[kk][uu * 4];
      float a0 = Alds[rg * 4 + 0][kk], a1 = Alds[rg * 4 + 1][kk];
      float a2 = Alds[rg * 4 + 2][kk], a3 = Alds[rg * 4 + 3][kk];
      acc[0][0] += a0 * w.x; acc[0][1] += a0 * w.y; acc[0][2] += a0 * w.z; acc[0][3] += a0 * w.w;
      acc[1][0] += a1 * w.x; acc[1][1] += a1 * w.y; acc[1][2] += a1 * w.z; acc[1][3] += a1 * w.w;
      acc[2][0] += a2 * w.x; acc[2][1] += a2 * w.y; acc[2][2] += a2 * w.z; acc[2][3] += a2 * w.w;
      acc[3][0] += a3 * w.x; acc[3][1] += a3 * w.y; acc[3][2] += a3 * w.z; acc[3][3] += a3 * w.w;
    }
  }
#pragma unroll
  for (int ri = 0; ri < 4; ++ri) {
    int m = m0 + rg * 4 + ri;
    float4 v = make_float4(acc[ri][0], acc[ri][1], acc[ri][2], acc[ri][3]);
    *(float4*)&C[(long)m * ldc + n0 + uu * 4] = v;
  }
}

}  // namespace

extern "C" void kernel_launch(void* const* d_in, const int* in_sizes, int n_in,
                              void* d_out, int out_size, void* d_ws, size_t ws_size,
                              hipStream_t stream) {
  const int* idxQ    = (const int*)d_in[1];
  const int* idxC    = (const int*)d_in[2];
  const int* idxC2   = (const int*)d_in[3];
  const float* hQ    = (const float*)d_in[4];
  const float* cQ    = (const float*)d_in[5];
  const float* hC    = (const float*)d_in[6];
  const float* cC    = (const float*)d_in[7];
  const float* hC2   = (const float*)d_in[8];
  const float* cC2   = (const float*)d_in[9];
  const float* emb   = (const float*)d_in[10];
  const float* Wih_f = (const float*)d_in[11];
  const float* Whh_f = (const float*)d_in[12];
  const float* bih_f = (const float*)d_in[13];
  const float* bhh_f = (const float*)d_in[14];
  const float* Wih_b = (const float*)d_in[15];
  const float* Whh_b = (const float*)d_in[16];
  const float* bih_b = (const float*)d_in[17];
  const float* bhh_b = (const float*)d_in[18];
  const float* S1W   = (const float*)d_in[19];
  const float* S1b   = (const float*)d_in[20];
  float* out = (float*)d_out;

  const long V = 50000;
  const long OUT1 = (long)B * S * 2 * H;   // 8,388,608 floats per input

  // -------- fast-path workspace layout (bytes) --------
  size_t off = 0;
  auto alloc = [&](size_t bytes) { size_t o = off; off += (bytes + 255) & ~(size_t)255; return o; };
  const size_t o_o3h  = alloc((size_t)3 * B * S * 512 * 2);
  const size_t o_o3l  = alloc((size_t)3 * B * S * 512 * 2);
  const size_t o_embH = alloc((size_t)V * E * 2);
  const size_t o_embL = alloc((size_t)V * E * 2);
  const size_t o_wihHf = alloc(1024 * 256 * 2), o_wihLf = alloc(1024 * 256 * 2);
  const size_t o_wihHb = alloc(1024 * 256 * 2), o_wihLb = alloc(1024 * 256 * 2);
  const size_t o_whhHf = alloc(1024 * 256 * 2), o_whhLf = alloc(1024 * 256 * 2);
  const size_t o_whhHb = alloc(1024 * 256 * 2), o_whhLb = alloc(1024 * 256 * 2);
  const size_t o_s1H  = alloc(512 * 512 * 2), o_s1L = alloc(512 * 512 * 2);
  const size_t o_bintf = alloc(1024 * 4), o_bintb = alloc(1024 * 4);
  const size_t o_hP   = alloc((size_t)2 * 6 * B * H * 4);   // packed hi|lo u32, 2 parities
  const size_t o_cst  = alloc((size_t)6 * B * H * 4);
  const size_t o_gen  = alloc(6 * 256 * 4);
  const size_t o_ctH  = alloc((size_t)B * S * 512 * 2);
  const size_t o_ctL  = alloc((size_t)B * S * 512 * 2);
  const size_t o_Hm   = alloc((size_t)B * S * S * 4);
  const size_t o_Ph   = alloc((size_t)B * S * S * 2);
  const size_t o_Pl   = alloc((size_t)B * S * S * 2);
  const size_t o_QtH  = alloc((size_t)B * 512 * 128 * 2);
  const size_t o_QtL  = alloc((size_t)B * 512 * 128 * 2);
  const size_t o_MQtH = alloc((size_t)B * 512 * 128 * 2);
  const size_t o_MQtL = alloc((size_t)B * 512 * 128 * 2);
  const size_t need_fast = off;   // ~260 MB

  if (ws_size >= need_fast) {
    char* base = (char*)d_ws;
    u16* o3h = (u16*)(base + o_o3h);
    u16* o3l = (u16*)(base + o_o3l);
    u16* embH = (u16*)(base + o_embH);
    u16* embL = (u16*)(base + o_embL);
    u16* wihHf = (u16*)(base + o_wihHf); u16* wihLf = (u16*)(base + o_wihLf);
    u16* wihHb = (u16*)(base + o_wihHb); u16* wihLb = (u16*)(base + o_wihLb);
    u16* whhHf = (u16*)(base + o_whhHf); u16* whhLf = (u16*)(base + o_whhLf);
    u16* whhHb = (u16*)(base + o_whhHb); u16* whhLb = (u16*)(base + o_whhLb);
    u16* s1H = (u16*)(base + o_s1H); u16* s1L = (u16*)(base + o_s1L);
    float* bintf = (float*)(base + o_bintf);
    float* bintb = (float*)(base + o_bintb);
    unsigned* hP = (unsigned*)(base + o_hP);
    float* cst = (float*)(base + o_cst);
    int* gen = (int*)(base + o_gen);
    u16* ctH = (u16*)(base + o_ctH);
    u16* ctL = (u16*)(base + o_ctL);
    float* Hm = (float*)(base + o_Hm);
    u16* Ph = (u16*)(base + o_Ph);
    u16* Pl = (u16*)(base + o_Pl);
    u16* QtH = (u16*)(base + o_QtH);
    u16* QtL = (u16*)(base + o_QtL);
    u16* MQtH = (u16*)(base + o_MQtH);
    u16* MQtL = (u16*)(base + o_MQtL);

    // ---- prep ----
    split_pair<<<(int)((V * E + 255) / 256), 256, 0, stream>>>(emb, embH, embL, V * E);
    split_w_int<<<1024, 256, 0, stream>>>(Wih_f, wihHf, wihLf);
    split_w_int<<<1024, 256, 0, stream>>>(Wih_b, wihHb, wihLb);
    split_w_int<<<1024, 256, 0, stream>>>(Whh_f, whhHf, whhLf);
    split_w_int<<<1024, 256, 0, stream>>>(Whh_b, whhHb, whhLb);
    split_pair<<<1024, 256, 0, stream>>>(S1W, s1H, s1L, 512 * 512);
    make_bint<<<4, 256, 0, stream>>>(bih_f, bhh_f, bintf);
    make_bint<<<4, 256, 0, stream>>>(bih_b, bhh_b, bintb);
    init_hc<<<(6 * B * H + 255) / 256, 256, 0, stream>>>(hQ, cQ, hC, cC, hC2, cC2, hP, cst);
    zero_gen<<<1, 64, 0, stream>>>(gen);

    // ---- LSTM: single cooperative launch, all 128 steps ----
    {
      const int* a0 = idxQ; const int* a1 = idxC; const int* a2 = idxC2;
      const u16* a3 = embH; const u16* a4 = embL;
      const u16* a5 = wihHf; const u16* a6 = wihLf;
      const u16* a7 = wihHb; const u16* a8 = wihLb;
      const u16* a9 = whhHf; const u16* a10 = whhLf;
      const u16* a11 = whhHb; const u16* a12 = whhLb;
      const float* a13 = bintf; const float* a14 = bintb;
      unsigned* a15 = hP; const float* a16 = cst;
      u16* a17 = o3h; u16* a18 = o3l; int* a19 = gen;
      void* kargs[] = {(void*)&a0, (void*)&a1, (void*)&a2, (void*)&a3, (void*)&a4,
                       (void*)&a5, (void*)&a6, (void*)&a7, (void*)&a8, (void*)&a9,
                       (void*)&a10, (void*)&a11, (void*)&a12, (void*)&a13, (void*)&a14,
                       (void*)&a15, (void*)&a16, (void*)&a17, (void*)&a18, (void*)&a19};
      hipLaunchCooperativeKernel((const void*)lstm_fused, dim3(128), dim3(256),
                                 kargs, 0, stream);
    }

    // ---- attention x2 ----
    transpose_qt<<<dim3(8, 2, 128), 256, 0, stream>>>(o3h, o3l, QtH, QtL);
    for (int p = 0; p < 2; ++p) {
      const u16* aH = o3h + (size_t)(1 + p) * B * S * 512;
      const u16* aL = o3l + (size_t)(1 + p) * B * S * 512;
      ct_mfma<<<dim3(4, 128), 256, 0, stream>>>(aH, aL, s1H, s1L, S1b, ctH, ctL);
      hm_mfma<<<128, 256, 0, stream>>>(o3h, o3l, ctH, ctL, Hm);
      softmax_row_bf<<<B * S, 64, 0, stream>>>(Hm, Ph, Pl);
      float* MQ = out + (long)(2 * p) * OUT1;
      pq_mfma<true><<<dim3(4, 1, 128), 256, 0, stream>>>(
          Ph, Pl, QtH, QtL, MQ, MQtH, MQtL);
      softmax_colT_bf<<<B * S, 64, 0, stream>>>(Hm, Ph, Pl);
      float* MC = out + (long)(2 * p + 1) * OUT1;
      pq_mfma<false><<<dim3(4, 1, 128), 256, 0, stream>>>(
          Ph, Pl, MQtH, MQtL, MC, nullptr, nullptr);
    }
    return;
  }

  // -------- fallback path: round-1 verified --------
  const long ST = (long)6 * B * H;
  float* ws    = (float*)d_ws;
  float* out3  = ws;
  float* hbuf0 = out3 + 3 * OUT1;
  float* hbuf1 = hbuf0 + ST;
  float* cbuf  = hbuf1 + ST;
  float* Ct    = cbuf + ST;
  float* Hm    = Ct + OUT1;
  float* Ab    = Hm + (long)B * S * S;

  init_state<<<(6 * B * H + 255) / 256, 256, 0, stream>>>(hQ, cQ, hC, cC, hC2, cC2, hbuf0, cbuf);

  for (int t = 0; t < S; ++t) {
    float* hr = (t & 1) ? hbuf1 : hbuf0;
    float* hw = (t & 1) ? hbuf0 : hbuf1;
    lstm_step<<<dim3(16, 2, 6), 256, 0, stream>>>(
        idxQ, idxC, idxC2, emb,
        Wih_f, Whh_f, bih_f, bhh_f, Wih_b, Whh_b, bih_b, bhh_b,
        hr, hw, cbuf, out3, t);
  }

  for (int p = 0; p < 2; ++p) {
    const float* Q  = out3;
    const float* C0 = out3 + (long)(1 + p) * OUT1;
    gemm_nt<true><<<dim3(8, 256, 1), 256, 0, stream>>>(
        C0, S1W, S1b, Ct, 512, 512, 512, 512, 0, 0, 0);
    gemm_nt<false><<<dim3(2, 2, B), 256, 0, stream>>>(
        Q, Ct, nullptr, Hm, 512, 512, 128, 512,
        (long)S * 512, (long)S * 512, (long)S * S);
    softmax_row<<<B * S, 64, 0, stream>>>(Hm, Ab);
    float* MQ = out + (long)(2 * p) * OUT1;
    gemm_nn<<<dim3(8, 2, B), 256, 0, stream>>>(
        Ab, Q, MQ, 128, 512, 512, 128,
        (long)S * S, (long)S * 512, (long)S * 512);
    softmax_colT<<<B * S, 64, 0, stream>>>(Hm, Ab);
    float* MC = out + (long)(2 * p + 1) * OUT1;
    gemm_nn<<<dim3(8, 2, B), 256, 0, stream>>>(
        Ab, MQ, MC, 128, 512, 512, 128,
        (long)S * S, (long)S * 512, (long)S * 512);
  }
}